// Round 2
// baseline (97.452 us; speedup 1.0000x reference)
//
#include <hip/hip_runtime.h>
#include <math.h>

#define HIDDEN       128
#define TABLE_N      2048
#define SMAX         10.0f
#define E            8           // table entries per block
#define TB_THREADS   128         // one thread per hidden unit
#define MAIN_THREADS 256
#define EPS2         0.01f
#define MASS_EPS     1e-8f
#define W2PAD        (HIDDEN + 1)   // 129: conflict-free row AND column LDS access

// ---------------------------------------------------------------------------
// Kernel 1: tabulate g(s) = d/ds [ W3·silu(W2·silu(W1*s+b1)+b2) + b3 ]
// for s = t * SMAX/(TABLE_N-1), t = 0..TABLE_N-1.
// W2 (64 KB) is staged into LDS once per block with coalesced float4 loads;
// both matvec loops then run out of LDS (pad 129 -> conflict-free both ways).
// Also stashes minv[0..2] at table[TABLE_N..TABLE_N+2] (outside interp range).
// ---------------------------------------------------------------------------
__global__ __launch_bounds__(TB_THREADS)
void build_table_kernel(const float* __restrict__ W1,
                        const float* __restrict__ b1,
                        const float* __restrict__ W2,
                        const float* __restrict__ b2,
                        const float* __restrict__ W3,
                        const float* __restrict__ logm,
                        float* __restrict__ table)
{
    const int tid = threadIdx.x;            // hidden unit index 0..127
    const int e0  = blockIdx.x * E;         // first table entry of this block
    __shared__ float w2s[HIDDEN * W2PAD];   // 66048 B, padded row-major
    __shared__ float sh[HIDDEN * E];        // 4 KB scratch (h1 / a / partials)

    // ---- stage W2 -> LDS, coalesced float4 global reads ----
    {
        const float4* w2v = (const float4*)W2;          // 4096 float4
        #pragma unroll
        for (int k = 0; k < (HIDDEN * HIDDEN / 4) / TB_THREADS; ++k) {  // 32
            int idx = k * TB_THREADS + tid;
            float4 v = w2v[idx];
            int fi  = idx << 2;
            int row = fi >> 7;
            int col = fi & (HIDDEN - 1);
            float* dst = &w2s[row * W2PAD + col];
            dst[0] = v.x; dst[1] = v.y; dst[2] = v.z; dst[3] = v.w;
        }
    }

    if (blockIdx.x == 0 && tid < 3)
        table[TABLE_N + tid] = 1.0f / (expf(logm[tid]) + MASS_EPS);

    const float ds  = SMAX / (float)(TABLE_N - 1);
    const float w1  = W1[tid];
    const float bb1 = b1[tid];

    // forward layer 1: h1 = silu(W1*s + b1); keep silu'(u1) in regs
    float sp1[E];
    #pragma unroll
    for (int e = 0; e < E; ++e) {
        float s  = (float)(e0 + e) * ds;
        float u1 = w1 * s + bb1;
        float sg = 1.0f / (1.0f + expf(-u1));
        sh[tid * E + e] = u1 * sg;                      // h1
        sp1[e] = sg * (1.0f + u1 * (1.0f - sg));        // silu'(u1)
    }
    __syncthreads();   // covers both W2 staging and h1 stores

    // forward layer 2: u2_i = b2_i + sum_j W2[i][j] h1_j
    // LDS row access: banks (tid+j)%32 -> conflict-free; sh read is broadcast
    float u2[E];
    #pragma unroll
    for (int e = 0; e < E; ++e) u2[e] = b2[tid];
    for (int j = 0; j < HIDDEN; ++j) {
        float w = w2s[tid * W2PAD + j];
        #pragma unroll
        for (int e = 0; e < E; ++e) u2[e] += w * sh[j * E + e];
    }

    // a_i = W3_i * silu'(u2_i)
    const float w3 = W3[tid];
    float a[E];
    #pragma unroll
    for (int e = 0; e < E; ++e) {
        float sg = 1.0f / (1.0f + expf(-u2[e]));
        a[e] = w3 * sg * (1.0f + u2[e] * (1.0f - sg));
    }
    __syncthreads();
    #pragma unroll
    for (int e = 0; e < E; ++e) sh[tid * E + e] = a[e];
    __syncthreads();

    // backward through W2: gv_j = sum_i W2[i][j] a_i
    // LDS column access: banks (129i+tid)%32 -> conflict-free
    float gv[E];
    #pragma unroll
    for (int e = 0; e < E; ++e) gv[e] = 0.0f;
    for (int i = 0; i < HIDDEN; ++i) {
        float w = w2s[i * W2PAD + tid];
        #pragma unroll
        for (int e = 0; e < E; ++e) gv[e] += w * sh[i * E + e];
    }
    __syncthreads();

    // partial_j = W1_j * silu'(u1_j) * gv_j ; block-reduce over j
    #pragma unroll
    for (int e = 0; e < E; ++e) sh[tid * E + e] = w1 * sp1[e] * gv[e];
    __syncthreads();
    if (tid < E) {
        float g = 0.0f;
        for (int j = 0; j < HIDDEN; ++j) g += sh[j * E + tid];
        table[e0 + tid] = g;
    }
}

// ---------------------------------------------------------------------------
// Kernel 2: streaming gradient field. One thread per sample.
// dqdt = p * minv ; dpdt accumulates g(s)*s^3*diff over the 3 pairs.
// float4 global<->LDS staging for coalescing; minv read from table stash
// (uniform scalar loads, no transcendentals in the hot kernel).
// ---------------------------------------------------------------------------
__global__ __launch_bounds__(MAIN_THREADS)
void hnn_grad_kernel(const float4* __restrict__ z4,
                     const float* __restrict__ table,
                     float4* __restrict__ out4)
{
    __shared__ alignas(16) float buf[MAIN_THREADS * 18];   // 18 KB
    float4* bufv = (float4*)buf;
    const int tid = threadIdx.x;
    const long long base4 = (long long)blockIdx.x * (MAIN_THREADS * 18 / 4); // 1152

    // coalesced global -> LDS stage (4 full float4 rounds + half round)
    #pragma unroll
    for (int k = 0; k < 4; ++k)
        bufv[k * MAIN_THREADS + tid] = z4[base4 + k * MAIN_THREADS + tid];
    if (tid < MAIN_THREADS / 2)
        bufv[4 * MAIN_THREADS + tid] = z4[base4 + 4 * MAIN_THREADS + tid];
    __syncthreads();

    float q[9], p[9];
    #pragma unroll
    for (int c = 0; c < 9; ++c) q[c] = buf[tid * 18 + c];
    #pragma unroll
    for (int c = 0; c < 9; ++c) p[c] = buf[tid * 18 + 9 + c];

    const float minv0 = table[TABLE_N + 0];
    const float minv1 = table[TABLE_N + 1];
    const float minv2 = table[TABLE_N + 2];

    float dq[9], dp[9];
    #pragma unroll
    for (int c = 0; c < 3; ++c) {
        dq[c]     = p[c]     * minv0;
        dq[3 + c] = p[3 + c] * minv1;
        dq[6 + c] = p[6 + c] * minv2;
    }
    #pragma unroll
    for (int c = 0; c < 9; ++c) dp[c] = 0.0f;

    const float scale = (float)(TABLE_N - 1) / SMAX;
    const int pi[3] = {0, 0, 1};
    const int pj[3] = {1, 2, 2};
    #pragma unroll
    for (int k = 0; k < 3; ++k) {
        const int i = pi[k] * 3, j = pj[k] * 3;
        float dx = q[i]     - q[j];
        float dy = q[i + 1] - q[j + 1];
        float dz = q[i + 2] - q[j + 2];
        float r2 = dx * dx + dy * dy + dz * dz + EPS2;
        float s  = 1.0f / sqrtf(r2);        // s <= 10 by construction (EPS2)
        // linear-interp table lookup of g(s) = dv/ds
        float x  = s * scale;
        int  idx = (int)x;
        idx = idx > (TABLE_N - 2) ? (TABLE_N - 2) : idx;   // never touches stash
        float f  = x - (float)idx;
        float t0 = table[idx], t1 = table[idx + 1];
        float g  = t0 + f * (t1 - t0);
        // dV/dq_i = g * ds/dq_i = -g*s^3*diff  =>  dp_i += g*s^3*diff
        float w = g * s * s * s;
        dp[i]     += w * dx;  dp[i + 1] += w * dy;  dp[i + 2] += w * dz;
        dp[j]     -= w * dx;  dp[j + 1] -= w * dy;  dp[j + 2] -= w * dz;
    }

    __syncthreads();   // all row-reads done before overwrite
    #pragma unroll
    for (int c = 0; c < 9; ++c) buf[tid * 18 + c]     = dq[c];
    #pragma unroll
    for (int c = 0; c < 9; ++c) buf[tid * 18 + 9 + c] = dp[c];
    __syncthreads();

    // coalesced LDS -> global float4 store
    #pragma unroll
    for (int k = 0; k < 4; ++k)
        out4[base4 + k * MAIN_THREADS + tid] = bufv[k * MAIN_THREADS + tid];
    if (tid < MAIN_THREADS / 2)
        out4[base4 + 4 * MAIN_THREADS + tid] = bufv[4 * MAIN_THREADS + tid];
}

// ---------------------------------------------------------------------------
extern "C" void kernel_launch(void* const* d_in, const int* in_sizes, int n_in,
                              void* d_out, int out_size, void* d_ws, size_t ws_size,
                              hipStream_t stream)
{
    const float* z   = (const float*)d_in[0];   // (B, 18)
    const float* lm  = (const float*)d_in[1];   // (3,)
    const float* W1  = (const float*)d_in[2];   // (128,1) flat
    const float* b1  = (const float*)d_in[3];   // (128,)
    const float* W2  = (const float*)d_in[4];   // (128,128) row-major
    const float* b2  = (const float*)d_in[5];   // (128,)
    const float* W3  = (const float*)d_in[6];   // (1,128) flat
    // d_in[7] = b3: constant offset, zero gradient -> unused
    float* table = (float*)d_ws;                // TABLE_N + 3 floats scratch

    hipLaunchKernelGGL(build_table_kernel, dim3(TABLE_N / E), dim3(TB_THREADS),
                       0, stream, W1, b1, W2, b2, W3, lm, table);

    const int B = in_sizes[0] / 18;             // 262144
    hipLaunchKernelGGL(hnn_grad_kernel, dim3(B / MAIN_THREADS), dim3(MAIN_THREADS),
                       0, stream, (const float4*)z, table, (float4*)d_out);
}

// Round 4
// 94.797 us; speedup vs baseline: 1.0280x; 1.0280x over previous
//
#include <hip/hip_runtime.h>
#include <math.h>

#define HIDDEN       128
#define TABLE_N      2048
#define SMAX         10.0f
#define E            8           // table entries per block
#define TB_THREADS   256
#define MAIN_THREADS 256
#define EPS2         0.01f
#define MASS_EPS     1e-8f
#define W2PAD        (HIDDEN + 1)   // 129: conflict-free row AND column LDS access

typedef float vf4 __attribute__((ext_vector_type(4)));   // native vec for nontemporal

// ---------------------------------------------------------------------------
// Kernel 1: tabulate g(s) = d/ds [ W3·silu(W2·silu(W1*s+b1)+b2) + b3 ]
// for s = t * SMAX/(TABLE_N-1), t = 0..TABLE_N-1.
// 256 threads: unit = tid&127, half = tid>>7. Both matvec loops are split
// across halves (64 iters each) with LDS partial-combine -> critical path /2.
// W2 staged once into LDS (pad 129 -> conflict-free row AND column access).
// Stashes minv[0..2] at table[TABLE_N..TABLE_N+2].
// ---------------------------------------------------------------------------
__global__ __launch_bounds__(TB_THREADS)
void build_table_kernel(const float* __restrict__ W1,
                        const float* __restrict__ b1,
                        const float* __restrict__ W2,
                        const float* __restrict__ b2,
                        const float* __restrict__ W3,
                        const float* __restrict__ logm,
                        float* __restrict__ table)
{
    const int tid  = threadIdx.x;
    const int unit = tid & 127;
    const int half = tid >> 7;                // 0 or 1
    const int e0   = blockIdx.x * E;

    __shared__ float w2s[HIDDEN * W2PAD];     // 66048 B
    __shared__ float sh[HIDDEN * E];          // 4 KB: h1 -> a -> pj
    __shared__ float part[TB_THREADS * E];    // 8 KB: split-loop partials

    // ---- stage W2 -> LDS, coalesced float4 ----
    {
        const vf4* w2v = (const vf4*)W2;            // 4096 float4
        #pragma unroll
        for (int k = 0; k < 16; ++k) {
            int idx = k * TB_THREADS + tid;
            vf4 v = w2v[idx];
            int fi  = idx << 2;
            int row = fi >> 7;
            int col = fi & (HIDDEN - 1);
            float* dst = &w2s[row * W2PAD + col];
            dst[0] = v.x; dst[1] = v.y; dst[2] = v.z; dst[3] = v.w;
        }
    }

    if (blockIdx.x == 0 && tid < 3)
        table[TABLE_N + tid] = 1.0f / (expf(logm[tid]) + MASS_EPS);

    const float ds  = SMAX / (float)(TABLE_N - 1);
    const float w1  = W1[unit];
    const float bb1 = b1[unit];

    // layer 1: h1 = silu(W1*s+b1); keep silu'(u1) in regs (both halves compute)
    float sp1[E];
    #pragma unroll
    for (int e = 0; e < E; ++e) {
        float s  = (float)(e0 + e) * ds;
        float u1 = w1 * s + bb1;
        float sg = 1.0f / (1.0f + expf(-u1));
        if (half == 0) sh[unit * E + e] = u1 * sg;          // h1
        sp1[e] = sg * (1.0f + u1 * (1.0f - sg));
    }
    __syncthreads();   // w2s + h1 ready

    // layer 2: u2_i = b2_i + sum_j W2[i][j] h1_j — j-range split by half
    float acc[E];
    #pragma unroll
    for (int e = 0; e < E; ++e) acc[e] = 0.0f;
    const int jb = half * 64;
    for (int j = 0; j < 64; ++j) {
        float w = w2s[unit * W2PAD + jb + j];
        #pragma unroll
        for (int e = 0; e < E; ++e) acc[e] += w * sh[(jb + j) * E + e];
    }
    #pragma unroll
    for (int e = 0; e < E; ++e) part[tid * E + e] = acc[e];
    __syncthreads();

    // combine u2; a_i = W3_i * silu'(u2_i); overwrite sh with a
    if (half == 0) {
        const float w3 = W3[unit];
        const float bb2 = b2[unit];
        #pragma unroll
        for (int e = 0; e < E; ++e) {
            float u2 = part[unit * E + e] + part[(unit + 128) * E + e] + bb2;
            float sg = 1.0f / (1.0f + expf(-u2));
            sh[unit * E + e] = w3 * sg * (1.0f + u2 * (1.0f - sg));
        }
    }
    __syncthreads();

    // backward: gv_j = sum_i W2[i][j] a_i — i-range split by half
    #pragma unroll
    for (int e = 0; e < E; ++e) acc[e] = 0.0f;
    const int ib = half * 64;
    for (int i = 0; i < 64; ++i) {
        float w = w2s[(ib + i) * W2PAD + unit];
        #pragma unroll
        for (int e = 0; e < E; ++e) acc[e] += w * sh[(ib + i) * E + e];
    }
    #pragma unroll
    for (int e = 0; e < E; ++e) part[tid * E + e] = acc[e];
    __syncthreads();

    // combine gv; pj = W1_j * silu'(u1_j) * gv_j; overwrite sh with pj
    if (half == 0) {
        #pragma unroll
        for (int e = 0; e < E; ++e) {
            float gv = part[unit * E + e] + part[(unit + 128) * E + e];
            sh[unit * E + e] = w1 * sp1[e] * gv;
        }
    }
    __syncthreads();

    // reduce over j (two-stage): 128 threads sum 8-j chunks, then E threads
    if (tid < 128) {
        int e = tid & 7, chunk = tid >> 3;     // 16 chunks of 8 j's
        float s = 0.0f;
        #pragma unroll
        for (int j = 0; j < 8; ++j) s += sh[(chunk * 8 + j) * E + e];
        part[e * 16 + chunk] = s;
    }
    __syncthreads();
    if (tid < E) {
        float g = 0.0f;
        #pragma unroll
        for (int c = 0; c < 16; ++c) g += part[tid * 16 + c];
        table[e0 + tid] = g;
    }
}

// ---------------------------------------------------------------------------
// Kernel 2: streaming gradient field. One thread per sample.
// Table (8 KB) staged into LDS per block -> gathers hit LDS not L1.
// Nontemporal vf4 global loads/stores (each byte touched once).
// ---------------------------------------------------------------------------
__global__ __launch_bounds__(MAIN_THREADS)
void hnn_grad_kernel(const vf4* __restrict__ z4,
                     const float* __restrict__ table,
                     vf4* __restrict__ out4)
{
    __shared__ alignas(16) float buf[MAIN_THREADS * 18];   // 18 KB
    __shared__ alignas(16) float tl[TABLE_N + 4];          // 8 KB + stash
    vf4* bufv = (vf4*)buf;
    const int tid = threadIdx.x;
    const long long base4 = (long long)blockIdx.x * (MAIN_THREADS * 18 / 4); // 1152

    // table -> LDS (512 float4 = 2048 floats) + minv stash
    {
        const vf4* t4 = (const vf4*)table;
        vf4* tl4 = (vf4*)tl;
        tl4[tid]                = t4[tid];
        tl4[MAIN_THREADS + tid] = t4[MAIN_THREADS + tid];
        if (tid < 3) tl[TABLE_N + tid] = table[TABLE_N + tid];
    }

    // coalesced nontemporal global -> LDS stage
    #pragma unroll
    for (int k = 0; k < 4; ++k)
        bufv[k * MAIN_THREADS + tid] =
            __builtin_nontemporal_load(&z4[base4 + k * MAIN_THREADS + tid]);
    if (tid < MAIN_THREADS / 2)
        bufv[4 * MAIN_THREADS + tid] =
            __builtin_nontemporal_load(&z4[base4 + 4 * MAIN_THREADS + tid]);
    __syncthreads();

    float q[9], p[9];
    #pragma unroll
    for (int c = 0; c < 9; ++c) q[c] = buf[tid * 18 + c];
    #pragma unroll
    for (int c = 0; c < 9; ++c) p[c] = buf[tid * 18 + 9 + c];

    const float minv0 = tl[TABLE_N + 0];
    const float minv1 = tl[TABLE_N + 1];
    const float minv2 = tl[TABLE_N + 2];

    float dq[9], dp[9];
    #pragma unroll
    for (int c = 0; c < 3; ++c) {
        dq[c]     = p[c]     * minv0;
        dq[3 + c] = p[3 + c] * minv1;
        dq[6 + c] = p[6 + c] * minv2;
    }
    #pragma unroll
    for (int c = 0; c < 9; ++c) dp[c] = 0.0f;

    const float scale = (float)(TABLE_N - 1) / SMAX;
    const int pi[3] = {0, 0, 1};
    const int pj[3] = {1, 2, 2};
    #pragma unroll
    for (int k = 0; k < 3; ++k) {
        const int i = pi[k] * 3, j = pj[k] * 3;
        float dx = q[i]     - q[j];
        float dy = q[i + 1] - q[j + 1];
        float dz = q[i + 2] - q[j + 2];
        float r2 = dx * dx + dy * dy + dz * dz + EPS2;
        float s  = 1.0f / sqrtf(r2);        // s <= 10 by construction (EPS2)
        float x  = s * scale;
        int  idx = (int)x;
        idx = idx > (TABLE_N - 2) ? (TABLE_N - 2) : idx;
        float f  = x - (float)idx;
        float t0 = tl[idx], t1 = tl[idx + 1];
        float g  = t0 + f * (t1 - t0);
        // dV/dq_i = g * ds/dq_i = -g*s^3*diff  =>  dp_i += g*s^3*diff
        float w = g * s * s * s;
        dp[i]     += w * dx;  dp[i + 1] += w * dy;  dp[i + 2] += w * dz;
        dp[j]     -= w * dx;  dp[j + 1] -= w * dy;  dp[j + 2] -= w * dz;
    }

    __syncthreads();   // all row-reads done before overwrite
    #pragma unroll
    for (int c = 0; c < 9; ++c) buf[tid * 18 + c]     = dq[c];
    #pragma unroll
    for (int c = 0; c < 9; ++c) buf[tid * 18 + 9 + c] = dp[c];
    __syncthreads();

    // coalesced nontemporal LDS -> global store
    #pragma unroll
    for (int k = 0; k < 4; ++k)
        __builtin_nontemporal_store(bufv[k * MAIN_THREADS + tid],
                                    &out4[base4 + k * MAIN_THREADS + tid]);
    if (tid < MAIN_THREADS / 2)
        __builtin_nontemporal_store(bufv[4 * MAIN_THREADS + tid],
                                    &out4[base4 + 4 * MAIN_THREADS + tid]);
}

// ---------------------------------------------------------------------------
extern "C" void kernel_launch(void* const* d_in, const int* in_sizes, int n_in,
                              void* d_out, int out_size, void* d_ws, size_t ws_size,
                              hipStream_t stream)
{
    const float* z   = (const float*)d_in[0];   // (B, 18)
    const float* lm  = (const float*)d_in[1];   // (3,)
    const float* W1  = (const float*)d_in[2];   // (128,1) flat
    const float* b1  = (const float*)d_in[3];   // (128,)
    const float* W2  = (const float*)d_in[4];   // (128,128) row-major
    const float* b2  = (const float*)d_in[5];   // (128,)
    const float* W3  = (const float*)d_in[6];   // (1,128) flat
    // d_in[7] = b3: constant offset, zero gradient -> unused
    float* table = (float*)d_ws;                // TABLE_N + 3 floats scratch

    hipLaunchKernelGGL(build_table_kernel, dim3(TABLE_N / E), dim3(TB_THREADS),
                       0, stream, W1, b1, W2, b2, W3, lm, table);

    const int B = in_sizes[0] / 18;             // 262144
    hipLaunchKernelGGL(hnn_grad_kernel, dim3(B / MAIN_THREADS), dim3(MAIN_THREADS),
                       0, stream, (const vf4*)z, table, (vf4*)d_out);
}